// Round 4
// baseline (499.343 us; speedup 1.0000x reference)
//
#include <hip/hip_runtime.h>

#define NU 100000      // users
#define NI 50000       // items
#define NN 150000      // total nodes
#define DIM 128        // embedding dim
#define NE 2000000     // directed edges (symmetrized)
#define NP 1000000     // undirected pairs (edge k and k+NP are the two directions)
#define NB ((NN + 63) / 64)   // 2344 64-node buckets
#define NSH 64                // scatter shards
#define CAP 64                // slots per (shard,bucket) cell; Poisson(~14) P(>64)~2e-22
#define BCAP 4096             // adj entries reserved per bucket (64 nodes x CAP)

typedef _Float16 half8 __attribute__((ext_vector_type(8)));
typedef float  fx4 __attribute__((ext_vector_type(4)));   // clang vector: OK for nontemporal builtins
typedef int    ix4 __attribute__((ext_vector_type(4)));

#define PPT 4                              // pairs per scatter thread
#define SCB ((NP + 256*PPT - 1) / (256*PPT))   // 977 scatter blocks
#define CVB ((NN * DIM / 8 + 255) / 256)       // 9375 convert blocks (exact)

// ---------------- build: sharded scatter + fused fp16 convert ----------------
// Scatter blocks: shard = blockIdx & 63. Blocks round-robin across the 8 XCDs,
// so shard s runs only on XCD s%8 -> its (shard,bucket) cell payload region
// stays in that XCD's L2 (the property the round-1 per-node scatter lost at 2x
// cost). 4 pairs/thread: 8 returning atomics issued before the 8 dependent
// stores -> 4x outstanding fabric atomics per wave. Convert blocks are
// independent streaming work riding under the scatter blocks' atomic latency;
// all convert traffic is non-temporal (touch-once).
__global__ void build_kernel(const int* __restrict__ row, const int* __restrict__ col,
                             int* __restrict__ cfil, int* __restrict__ pairs,
                             const float* __restrict__ user, const float* __restrict__ item,
                             _Float16* __restrict__ x16) {
    int b = blockIdx.x;
    if (b < SCB) {
        int s = b & (NSH - 1);
        int base = b * (256 * PPT) + threadIdx.x;
        int u[PPT], v[PPT];
        bool ok[PPT];
        #pragma unroll
        for (int p = 0; p < PPT; p++) {
            int k = base + p * 256;
            ok[p] = (k < NP);
            if (ok[p]) {
                u[p] = __builtin_nontemporal_load(row + k);
                v[p] = __builtin_nontemporal_load(col + k);
            }
        }
        int p1[PPT], p2[PPT];
        #pragma unroll
        for (int p = 0; p < PPT; p++) {
            if (ok[p]) {
                p1[p] = atomicAdd(&cfil[s * NB + (v[p] >> 6)], 1);
                p2[p] = atomicAdd(&cfil[s * NB + (u[p] >> 6)], 1);
            }
        }
        #pragma unroll
        for (int p = 0; p < PPT; p++) {
            if (ok[p]) {
                if (p1[p] < CAP)
                    pairs[(size_t)(s * NB + (v[p] >> 6)) * CAP + p1[p]] = (u[p] << 6) | (v[p] & 63);
                if (p2[p] < CAP)
                    pairs[(size_t)(s * NB + (u[p] >> 6)) * CAP + p2[p]] = (v[p] << 6) | (u[p] & 63);
            }
        }
    } else {
        size_t t = (size_t)(b - SCB) * 256 + threadIdx.x;   // group of 8 floats
        size_t e = t * 8;
        if (e < (size_t)NN * DIM) {
            const size_t NUsz = (size_t)NU * DIM;
            const float* src = (e < NUsz) ? user + e : item + (e - NUsz);
            fx4 va = __builtin_nontemporal_load((const fx4*)src);
            fx4 vb = __builtin_nontemporal_load((const fx4*)(src + 4));
            half8 h;
            h[0] = (_Float16)va.x; h[1] = (_Float16)va.y;
            h[2] = (_Float16)va.z; h[3] = (_Float16)va.w;
            h[4] = (_Float16)vb.x; h[5] = (_Float16)vb.y;
            h[6] = (_Float16)vb.z; h[7] = (_Float16)vb.w;
            __builtin_nontemporal_store(*(const ix4*)&h, (ix4*)(x16 + e));
        }
    }
}

// Per bucket: read its 64 cells, LDS-count per node, wave-scan -> ptr/deg/dinv,
// then compact into the bucket's static adj region [b*BCAP, ...).
__global__ __launch_bounds__(256) void place_kernel(
    const int* __restrict__ cfil, const int* __restrict__ pairs,
    int* __restrict__ adj, int* __restrict__ ptr, int* __restrict__ deg,
    float* __restrict__ dinv) {
    __shared__ int lcnt[64];
    __shared__ int lptr[64];
    __shared__ int lfill[64];
    __shared__ int llen[64];
    int b = blockIdx.x;
    int t = threadIdx.x;
    if (t < 64) {
        lcnt[t] = 0;
        lfill[t] = 0;
        llen[t] = min(cfil[t * NB + b], CAP);
    }
    __syncthreads();
    // count: 16 threads per cell, 16 cells per pass
    for (int s = t >> 4; s < 64; s += 16) {
        const int* cp = pairs + (size_t)(s * NB + b) * CAP;
        int len = llen[s];
        for (int i = t & 15; i < len; i += 16)
            atomicAdd(&lcnt[cp[i] & 63], 1);
    }
    __syncthreads();
    if (t < 64) {   // threads 0..63 = lanes 0..63 of wave 0
        int v = lcnt[t];
        int incl = v;
        #pragma unroll
        for (int off = 1; off < 64; off <<= 1) {
            int u = __shfl_up(incl, off, 64);
            if (t >= off) incl += u;
        }
        lptr[t] = (b << 12) + incl - v;   // bucket's static adj base + prefix
        int c = (b << 6) + t;
        if (c < NN) {
            ptr[c] = lptr[t];
            deg[c] = v;
            dinv[c] = (v > 0) ? 1.0f / sqrtf((float)v) : 0.0f;
        }
    }
    __syncthreads();
    // place
    for (int s = t >> 4; s < 64; s += 16) {
        const int* cp = pairs + (size_t)(s * NB + b) * CAP;
        int len = llen[s];
        for (int i = t & 15; i < len; i += 16) {
            int pk = cp[i];
            int lc = pk & 63;
            int slot = lptr[lc] + atomicAdd(&lfill[lc], 1);
            adj[slot] = pk >> 6;
        }
    }
}

// ---------------- propagation (wide-gather, unroll-2) ----------------
// One wave per target node. 16 lanes cover one 256B row (8 halves/lane);
// 4 quads x 2 unrolled slots = 8 edges / iteration, 16 lines in flight.
// fp32 accumulate; fabric-roofline-bound (~3.5 TB/s random 256B granules;
// FETCH ~= 8 XCD x 38.4 MB = compulsory floor with private L2s).
// All touch-once streams (xout, out, x0/x1/x2 in finalize) are non-temporal
// so they don't evict the gather working set from L2.
__global__ __launch_bounds__(256) void prop_kernel(
    const _Float16* __restrict__ xin,
    const float* __restrict__ dinv, const int* __restrict__ ptr,
    const int* __restrict__ deg, const int* __restrict__ adj,
    _Float16* __restrict__ xout, int finalize,
    const _Float16* __restrict__ x0, const _Float16* __restrict__ x1,
    const _Float16* __restrict__ x2, float* __restrict__ out)
{
    int wid = (blockIdx.x * blockDim.x + threadIdx.x) >> 6;
    if (wid >= NN) return;
    int lane = threadIdx.x & 63;
    int q = lane >> 4;     // edge sub-slot 0..3
    int m = lane & 15;     // halves [8m, 8m+8) of the row
    int beg = ptr[wid];
    int end = beg + deg[wid];

    float a0 = 0.f, a1 = 0.f, a2 = 0.f, a3 = 0.f;
    float a4 = 0.f, a5 = 0.f, a6 = 0.f, a7 = 0.f;
    int j = beg;
    for (; j + 8 <= end; j += 8) {
        int r0 = adj[j + q];
        int r1 = adj[j + 4 + q];
        float w0 = dinv[r0];
        float w1 = dinv[r1];
        half8 v0 = *(const half8*)(xin + (size_t)r0 * DIM + 8 * m);
        half8 v1 = *(const half8*)(xin + (size_t)r1 * DIM + 8 * m);
        a0 += w0 * (float)v0[0] + w1 * (float)v1[0];
        a1 += w0 * (float)v0[1] + w1 * (float)v1[1];
        a2 += w0 * (float)v0[2] + w1 * (float)v1[2];
        a3 += w0 * (float)v0[3] + w1 * (float)v1[3];
        a4 += w0 * (float)v0[4] + w1 * (float)v1[4];
        a5 += w0 * (float)v0[5] + w1 * (float)v1[5];
        a6 += w0 * (float)v0[6] + w1 * (float)v1[6];
        a7 += w0 * (float)v0[7] + w1 * (float)v1[7];
    }
    if (j < end) {
        int jj0 = j + q;
        int jj1 = j + 4 + q;
        int r0 = adj[min(jj0, end - 1)];
        int r1 = adj[min(jj1, end - 1)];
        float w0 = (jj0 < end) ? dinv[r0] : 0.f;
        float w1 = (jj1 < end) ? dinv[r1] : 0.f;
        half8 v0 = *(const half8*)(xin + (size_t)r0 * DIM + 8 * m);
        half8 v1 = *(const half8*)(xin + (size_t)r1 * DIM + 8 * m);
        a0 += w0 * (float)v0[0] + w1 * (float)v1[0];
        a1 += w0 * (float)v0[1] + w1 * (float)v1[1];
        a2 += w0 * (float)v0[2] + w1 * (float)v1[2];
        a3 += w0 * (float)v0[3] + w1 * (float)v1[3];
        a4 += w0 * (float)v0[4] + w1 * (float)v1[4];
        a5 += w0 * (float)v0[5] + w1 * (float)v1[5];
        a6 += w0 * (float)v0[6] + w1 * (float)v1[6];
        a7 += w0 * (float)v0[7] + w1 * (float)v1[7];
    }
    a0 += __shfl_xor(a0, 16, 64); a1 += __shfl_xor(a1, 16, 64);
    a2 += __shfl_xor(a2, 16, 64); a3 += __shfl_xor(a3, 16, 64);
    a4 += __shfl_xor(a4, 16, 64); a5 += __shfl_xor(a5, 16, 64);
    a6 += __shfl_xor(a6, 16, 64); a7 += __shfl_xor(a7, 16, 64);
    a0 += __shfl_xor(a0, 32, 64); a1 += __shfl_xor(a1, 32, 64);
    a2 += __shfl_xor(a2, 32, 64); a3 += __shfl_xor(a3, 32, 64);
    a4 += __shfl_xor(a4, 32, 64); a5 += __shfl_xor(a5, 32, 64);
    a6 += __shfl_xor(a6, 32, 64); a7 += __shfl_xor(a7, 32, 64);

    if (q != 0) return;
    float dc = dinv[wid];
    float n0 = dc * a0, n1 = dc * a1, n2 = dc * a2, n3 = dc * a3;
    float n4 = dc * a4, n5 = dc * a5, n6 = dc * a6, n7 = dc * a7;

    if (!finalize) {
        half8 h;
        h[0] = (_Float16)n0; h[1] = (_Float16)n1; h[2] = (_Float16)n2; h[3] = (_Float16)n3;
        h[4] = (_Float16)n4; h[5] = (_Float16)n5; h[6] = (_Float16)n6; h[7] = (_Float16)n7;
        __builtin_nontemporal_store(*(const ix4*)&h, (ix4*)(xout + (size_t)wid * DIM + 8 * m));
    } else {
        size_t base = (size_t)wid * DIM + 8 * m;
        ix4 t0 = __builtin_nontemporal_load((const ix4*)(x0 + base));
        ix4 t1 = __builtin_nontemporal_load((const ix4*)(x1 + base));
        ix4 t2 = __builtin_nontemporal_load((const ix4*)(x2 + base));
        half8 f0 = *(const half8*)&t0;
        half8 f1 = *(const half8*)&t1;
        half8 f2 = *(const half8*)&t2;
        float* po = out + base;
        fx4 oa, ob;
        oa.x = ((float)f0[0] + (float)f1[0] + (float)f2[0] + n0) * 0.25f;
        oa.y = ((float)f0[1] + (float)f1[1] + (float)f2[1] + n1) * 0.25f;
        oa.z = ((float)f0[2] + (float)f1[2] + (float)f2[2] + n2) * 0.25f;
        oa.w = ((float)f0[3] + (float)f1[3] + (float)f2[3] + n3) * 0.25f;
        ob.x = ((float)f0[4] + (float)f1[4] + (float)f2[4] + n4) * 0.25f;
        ob.y = ((float)f0[5] + (float)f1[5] + (float)f2[5] + n5) * 0.25f;
        ob.z = ((float)f0[6] + (float)f1[6] + (float)f2[6] + n6) * 0.25f;
        ob.w = ((float)f0[7] + (float)f1[7] + (float)f2[7] + n7) * 0.25f;
        __builtin_nontemporal_store(oa, (fx4*)po);
        __builtin_nontemporal_store(ob, (fx4*)(po + 4));
    }
}

// ---------------- launch ----------------

extern "C" void kernel_launch(void* const* d_in, const int* in_sizes, int n_in,
                              void* d_out, int out_size, void* d_ws, size_t ws_size,
                              hipStream_t stream) {
    const int* edge = (const int*)d_in[0];      // [2, NE] int32
    const int* row = edge;                      // sources (first NP entries = users)
    const int* col = edge + NE;                 // targets (first NP entries = items)
    const float* user = (const float*)d_in[1];  // [NU, DIM]
    const float* item = (const float*)d_in[2];  // [NI, DIM]
    float* out = (float*)d_out;                 // [NN, DIM]

    char* ws = (char*)d_ws;
    size_t off = 0;
    auto alloc = [&](size_t bytes) -> void* {
        void* p = ws + off;
        off = (off + bytes + 255) & ~(size_t)255;
        return p;
    };
    _Float16* x0 = (_Float16*)alloc(sizeof(_Float16) * (size_t)NN * DIM);  // 38.4 MB
    _Float16* x1 = (_Float16*)alloc(sizeof(_Float16) * (size_t)NN * DIM);
    _Float16* x2 = (_Float16*)alloc(sizeof(_Float16) * (size_t)NN * DIM);
    float* dinv = (float*)alloc(sizeof(float) * NN);
    int*   cfil = (int*)  alloc(sizeof(int) * NSH * NB);              // 600 KB (zeroed)
    int*   ptr  = (int*)  alloc(sizeof(int) * NN);
    int*   deg  = (int*)  alloc(sizeof(int) * NN);
    int*   pairs= (int*)  alloc(sizeof(int) * (size_t)NSH * NB * CAP);// 38.4 MB
    int*   adj  = (int*)  alloc(sizeof(int) * (size_t)NB * BCAP);     // 38.4 MB

    (void)hipMemsetAsync(cfil, 0, sizeof(int) * NSH * NB, stream);
    build_kernel<<<SCB + CVB, 256, 0, stream>>>(row, col, cfil, pairs, user, item, x0);
    place_kernel<<<NB, 256, 0, stream>>>(cfil, pairs, adj, ptr, deg, dinv);

    int blocks = (NN + 3) / 4;  // 4 waves (nodes) per 256-thread block
    prop_kernel<<<blocks, 256, 0, stream>>>(x0, dinv, ptr, deg, adj, x1, 0,
                                            nullptr, nullptr, nullptr, nullptr);
    prop_kernel<<<blocks, 256, 0, stream>>>(x1, dinv, ptr, deg, adj, x2, 0,
                                            nullptr, nullptr, nullptr, nullptr);
    prop_kernel<<<blocks, 256, 0, stream>>>(x2, dinv, ptr, deg, adj, nullptr, 1,
                                            x0, x1, x2, out);
}

// Round 5
// 489.793 us; speedup vs baseline: 1.0195x; 1.0195x over previous
//
#include <hip/hip_runtime.h>

#define NU 100000      // users
#define NI 50000       // items
#define NN 150000      // total nodes
#define DIM 128        // embedding dim
#define NE 2000000     // directed edges (symmetrized)
#define NP 1000000     // undirected pairs (edge k and k+NP are the two directions)
#define NB ((NN + 63) / 64)   // 2344 64-node buckets
#define NSH 64                // scatter shards
#define CAP 64                // slots per (shard,bucket) cell; Poisson(~13) P(>64)~1e-22
#define BCAP 4096             // adj entries reserved per bucket (64 nodes x CAP)

typedef _Float16 half8 __attribute__((ext_vector_type(8)));

#define PPT 4                                  // pairs per scatter thread
#define SCB ((NP + 256*PPT - 1) / (256*PPT))   // 977 scatter blocks
#define CVB ((NN * DIM / 8 + 255) / 256)       // 9375 convert blocks (exact)

// ---------------- build: sharded scatter + fused fp16 convert ----------------
// Scatter blocks: shard = blockIdx & 63. Blocks round-robin across the 8 XCDs,
// so shard s runs only on XCD s%8 -> its (shard,bucket) cell payload region
// stays in that XCD's L2 (XCD-local atomics + writes). 4 pairs/thread: 8
// returning atomics issued back-to-back before the 8 dependent stores -> 4x
// outstanding fabric atomics per wave (build is latency-bound: VALUBusy ~1%,
// HBM ~11%). Convert blocks are independent streaming work riding under the
// scatter blocks' atomic latency. NOTE: no nontemporal hints anywhere — round-4
// measured nt as net-negative on gfx950 (pass-3 prop 104 -> 116 us).
__global__ void build_kernel(const int* __restrict__ row, const int* __restrict__ col,
                             int* __restrict__ cfil, int* __restrict__ pairs,
                             const float* __restrict__ user, const float* __restrict__ item,
                             _Float16* __restrict__ x16) {
    int b = blockIdx.x;
    if (b < SCB) {
        int s = b & (NSH - 1);
        int base = b * (256 * PPT) + threadIdx.x;
        int u[PPT], v[PPT];
        bool ok[PPT];
        #pragma unroll
        for (int p = 0; p < PPT; p++) {
            int k = base + p * 256;
            ok[p] = (k < NP);
            if (ok[p]) {
                u[p] = row[k];
                v[p] = col[k];
            }
        }
        int p1[PPT], p2[PPT];
        #pragma unroll
        for (int p = 0; p < PPT; p++) {
            if (ok[p]) {
                p1[p] = atomicAdd(&cfil[s * NB + (v[p] >> 6)], 1);
                p2[p] = atomicAdd(&cfil[s * NB + (u[p] >> 6)], 1);
            }
        }
        #pragma unroll
        for (int p = 0; p < PPT; p++) {
            if (ok[p]) {
                if (p1[p] < CAP)
                    pairs[(size_t)(s * NB + (v[p] >> 6)) * CAP + p1[p]] = (u[p] << 6) | (v[p] & 63);
                if (p2[p] < CAP)
                    pairs[(size_t)(s * NB + (u[p] >> 6)) * CAP + p2[p]] = (v[p] << 6) | (u[p] & 63);
            }
        }
    } else {
        size_t t = (size_t)(b - SCB) * 256 + threadIdx.x;   // group of 8 floats
        size_t e = t * 8;
        if (e < (size_t)NN * DIM) {
            const size_t NUsz = (size_t)NU * DIM;
            const float* src = (e < NUsz) ? user + e : item + (e - NUsz);
            float4 va = *(const float4*)src;
            float4 vb = *(const float4*)(src + 4);
            half8 h;
            h[0] = (_Float16)va.x; h[1] = (_Float16)va.y;
            h[2] = (_Float16)va.z; h[3] = (_Float16)va.w;
            h[4] = (_Float16)vb.x; h[5] = (_Float16)vb.y;
            h[6] = (_Float16)vb.z; h[7] = (_Float16)vb.w;
            *(half8*)(x16 + e) = h;
        }
    }
}

// Per bucket: read its 64 cells, LDS-count per node, wave-scan -> ptr/deg/dinv,
// then compact into the bucket's static adj region [b*BCAP, ...).
__global__ __launch_bounds__(256) void place_kernel(
    const int* __restrict__ cfil, const int* __restrict__ pairs,
    int* __restrict__ adj, int* __restrict__ ptr, int* __restrict__ deg,
    float* __restrict__ dinv) {
    __shared__ int lcnt[64];
    __shared__ int lptr[64];
    __shared__ int lfill[64];
    __shared__ int llen[64];
    int b = blockIdx.x;
    int t = threadIdx.x;
    if (t < 64) {
        lcnt[t] = 0;
        lfill[t] = 0;
        llen[t] = min(cfil[t * NB + b], CAP);
    }
    __syncthreads();
    // count: 16 threads per cell, 16 cells per pass
    for (int s = t >> 4; s < 64; s += 16) {
        const int* cp = pairs + (size_t)(s * NB + b) * CAP;
        int len = llen[s];
        for (int i = t & 15; i < len; i += 16)
            atomicAdd(&lcnt[cp[i] & 63], 1);
    }
    __syncthreads();
    if (t < 64) {   // threads 0..63 = lanes 0..63 of wave 0
        int v = lcnt[t];
        int incl = v;
        #pragma unroll
        for (int off = 1; off < 64; off <<= 1) {
            int u = __shfl_up(incl, off, 64);
            if (t >= off) incl += u;
        }
        lptr[t] = (b << 12) + incl - v;   // bucket's static adj base + prefix
        int c = (b << 6) + t;
        if (c < NN) {
            ptr[c] = lptr[t];
            deg[c] = v;
            dinv[c] = (v > 0) ? 1.0f / sqrtf((float)v) : 0.0f;
        }
    }
    __syncthreads();
    // place
    for (int s = t >> 4; s < 64; s += 16) {
        const int* cp = pairs + (size_t)(s * NB + b) * CAP;
        int len = llen[s];
        for (int i = t & 15; i < len; i += 16) {
            int pk = cp[i];
            int lc = pk & 63;
            int slot = lptr[lc] + atomicAdd(&lfill[lc], 1);
            adj[slot] = pk >> 6;
        }
    }
}

// ---------------- propagation (wide-gather, unroll-2) ----------------
// One wave per target node. 16 lanes cover one 256B row (8 halves/lane);
// 4 quads x 2 unrolled slots = 8 edges / iteration, 16 lines in flight.
// fp32 accumulate; fabric-roofline-bound (~3.58 TB/s effective, FETCH ~= 287 MB
// ~= per-XCD compulsory line coverage). Plain loads/stores only — nt measured
// net-negative here (round 4).
__global__ __launch_bounds__(256) void prop_kernel(
    const _Float16* __restrict__ xin,
    const float* __restrict__ dinv, const int* __restrict__ ptr,
    const int* __restrict__ deg, const int* __restrict__ adj,
    _Float16* __restrict__ xout, int finalize,
    const _Float16* __restrict__ x0, const _Float16* __restrict__ x1,
    const _Float16* __restrict__ x2, float* __restrict__ out)
{
    int wid = (blockIdx.x * blockDim.x + threadIdx.x) >> 6;
    if (wid >= NN) return;
    int lane = threadIdx.x & 63;
    int q = lane >> 4;     // edge sub-slot 0..3
    int m = lane & 15;     // halves [8m, 8m+8) of the row
    int beg = ptr[wid];
    int end = beg + deg[wid];

    float a0 = 0.f, a1 = 0.f, a2 = 0.f, a3 = 0.f;
    float a4 = 0.f, a5 = 0.f, a6 = 0.f, a7 = 0.f;
    int j = beg;
    for (; j + 8 <= end; j += 8) {
        int r0 = adj[j + q];
        int r1 = adj[j + 4 + q];
        float w0 = dinv[r0];
        float w1 = dinv[r1];
        half8 v0 = *(const half8*)(xin + (size_t)r0 * DIM + 8 * m);
        half8 v1 = *(const half8*)(xin + (size_t)r1 * DIM + 8 * m);
        a0 += w0 * (float)v0[0] + w1 * (float)v1[0];
        a1 += w0 * (float)v0[1] + w1 * (float)v1[1];
        a2 += w0 * (float)v0[2] + w1 * (float)v1[2];
        a3 += w0 * (float)v0[3] + w1 * (float)v1[3];
        a4 += w0 * (float)v0[4] + w1 * (float)v1[4];
        a5 += w0 * (float)v0[5] + w1 * (float)v1[5];
        a6 += w0 * (float)v0[6] + w1 * (float)v1[6];
        a7 += w0 * (float)v0[7] + w1 * (float)v1[7];
    }
    if (j < end) {
        int jj0 = j + q;
        int jj1 = j + 4 + q;
        int r0 = adj[min(jj0, end - 1)];
        int r1 = adj[min(jj1, end - 1)];
        float w0 = (jj0 < end) ? dinv[r0] : 0.f;
        float w1 = (jj1 < end) ? dinv[r1] : 0.f;
        half8 v0 = *(const half8*)(xin + (size_t)r0 * DIM + 8 * m);
        half8 v1 = *(const half8*)(xin + (size_t)r1 * DIM + 8 * m);
        a0 += w0 * (float)v0[0] + w1 * (float)v1[0];
        a1 += w0 * (float)v0[1] + w1 * (float)v1[1];
        a2 += w0 * (float)v0[2] + w1 * (float)v1[2];
        a3 += w0 * (float)v0[3] + w1 * (float)v1[3];
        a4 += w0 * (float)v0[4] + w1 * (float)v1[4];
        a5 += w0 * (float)v0[5] + w1 * (float)v1[5];
        a6 += w0 * (float)v0[6] + w1 * (float)v1[6];
        a7 += w0 * (float)v0[7] + w1 * (float)v1[7];
    }
    a0 += __shfl_xor(a0, 16, 64); a1 += __shfl_xor(a1, 16, 64);
    a2 += __shfl_xor(a2, 16, 64); a3 += __shfl_xor(a3, 16, 64);
    a4 += __shfl_xor(a4, 16, 64); a5 += __shfl_xor(a5, 16, 64);
    a6 += __shfl_xor(a6, 16, 64); a7 += __shfl_xor(a7, 16, 64);
    a0 += __shfl_xor(a0, 32, 64); a1 += __shfl_xor(a1, 32, 64);
    a2 += __shfl_xor(a2, 32, 64); a3 += __shfl_xor(a3, 32, 64);
    a4 += __shfl_xor(a4, 32, 64); a5 += __shfl_xor(a5, 32, 64);
    a6 += __shfl_xor(a6, 32, 64); a7 += __shfl_xor(a7, 32, 64);

    if (q != 0) return;
    float dc = dinv[wid];
    float n0 = dc * a0, n1 = dc * a1, n2 = dc * a2, n3 = dc * a3;
    float n4 = dc * a4, n5 = dc * a5, n6 = dc * a6, n7 = dc * a7;

    if (!finalize) {
        half8 h;
        h[0] = (_Float16)n0; h[1] = (_Float16)n1; h[2] = (_Float16)n2; h[3] = (_Float16)n3;
        h[4] = (_Float16)n4; h[5] = (_Float16)n5; h[6] = (_Float16)n6; h[7] = (_Float16)n7;
        *(half8*)(xout + (size_t)wid * DIM + 8 * m) = h;
    } else {
        size_t base = (size_t)wid * DIM + 8 * m;
        half8 f0 = *(const half8*)(x0 + base);
        half8 f1 = *(const half8*)(x1 + base);
        half8 f2 = *(const half8*)(x2 + base);
        float* po = out + base;
        float4 oa, ob;
        oa.x = ((float)f0[0] + (float)f1[0] + (float)f2[0] + n0) * 0.25f;
        oa.y = ((float)f0[1] + (float)f1[1] + (float)f2[1] + n1) * 0.25f;
        oa.z = ((float)f0[2] + (float)f1[2] + (float)f2[2] + n2) * 0.25f;
        oa.w = ((float)f0[3] + (float)f1[3] + (float)f2[3] + n3) * 0.25f;
        ob.x = ((float)f0[4] + (float)f1[4] + (float)f2[4] + n4) * 0.25f;
        ob.y = ((float)f0[5] + (float)f1[5] + (float)f2[5] + n5) * 0.25f;
        ob.z = ((float)f0[6] + (float)f1[6] + (float)f2[6] + n6) * 0.25f;
        ob.w = ((float)f0[7] + (float)f1[7] + (float)f2[7] + n7) * 0.25f;
        *(float4*)(po) = oa;
        *(float4*)(po + 4) = ob;
    }
}

// ---------------- launch ----------------

extern "C" void kernel_launch(void* const* d_in, const int* in_sizes, int n_in,
                              void* d_out, int out_size, void* d_ws, size_t ws_size,
                              hipStream_t stream) {
    const int* edge = (const int*)d_in[0];      // [2, NE] int32
    const int* row = edge;                      // sources (first NP entries = users)
    const int* col = edge + NE;                 // targets (first NP entries = items)
    const float* user = (const float*)d_in[1];  // [NU, DIM]
    const float* item = (const float*)d_in[2];  // [NI, DIM]
    float* out = (float*)d_out;                 // [NN, DIM]

    char* ws = (char*)d_ws;
    size_t off = 0;
    auto alloc = [&](size_t bytes) -> void* {
        void* p = ws + off;
        off = (off + bytes + 255) & ~(size_t)255;
        return p;
    };
    _Float16* x0 = (_Float16*)alloc(sizeof(_Float16) * (size_t)NN * DIM);  // 38.4 MB
    _Float16* x1 = (_Float16*)alloc(sizeof(_Float16) * (size_t)NN * DIM);
    _Float16* x2 = (_Float16*)alloc(sizeof(_Float16) * (size_t)NN * DIM);
    float* dinv = (float*)alloc(sizeof(float) * NN);
    int*   cfil = (int*)  alloc(sizeof(int) * NSH * NB);              // 600 KB (zeroed)
    int*   ptr  = (int*)  alloc(sizeof(int) * NN);
    int*   deg  = (int*)  alloc(sizeof(int) * NN);
    int*   pairs= (int*)  alloc(sizeof(int) * (size_t)NSH * NB * CAP);// 38.4 MB
    int*   adj  = (int*)  alloc(sizeof(int) * (size_t)NB * BCAP);     // 38.4 MB

    (void)hipMemsetAsync(cfil, 0, sizeof(int) * NSH * NB, stream);
    build_kernel<<<SCB + CVB, 256, 0, stream>>>(row, col, cfil, pairs, user, item, x0);
    place_kernel<<<NB, 256, 0, stream>>>(cfil, pairs, adj, ptr, deg, dinv);

    int blocks = (NN + 3) / 4;  // 4 waves (nodes) per 256-thread block
    prop_kernel<<<blocks, 256, 0, stream>>>(x0, dinv, ptr, deg, adj, x1, 0,
                                            nullptr, nullptr, nullptr, nullptr);
    prop_kernel<<<blocks, 256, 0, stream>>>(x1, dinv, ptr, deg, adj, x2, 0,
                                            nullptr, nullptr, nullptr, nullptr);
    prop_kernel<<<blocks, 256, 0, stream>>>(x2, dinv, ptr, deg, adj, nullptr, 1,
                                            x0, x1, x2, out);
}

// Round 6
// 471.408 us; speedup vs baseline: 1.0593x; 1.0390x over previous
//
#include <hip/hip_runtime.h>

#define NU 100000      // users
#define NI 50000       // items
#define NN 150000      // total nodes
#define DIM 128        // embedding dim
#define NE 2000000     // directed edges (symmetrized)
#define NP 1000000     // undirected pairs (edge k and k+NP are the two directions)
#define NB ((NN + 63) / 64)   // 2344 64-node buckets
#define NSH 128               // scatter shards == scatter blocks (one block per shard)
#define CAP 32                // slots per (shard,bucket) cell; Poisson(6.7) P(>32)*600K cells ~ 3e-8
#define BCAP 4096             // adj entries reserved per bucket (64 nodes x 64)

typedef _Float16 half8 __attribute__((ext_vector_type(8)));
typedef _Float16 half4c __attribute__((ext_vector_type(4)));

#define PPS ((NP + NSH - 1) / NSH)            // 7813 pairs per shard block
#define CVB ((NN * DIM / 4 + 255) / 256)      // 18750 convert blocks (exact)

// ---------------- build: LDS-counter scatter + fused fp16 convert ----------------
// One block per shard: the shard's 2344 cell counters live in LDS, so the 2M
// returning GLOBAL atomics of the old design become LDS atomics (round-5
// showed global-atomic throughput, not per-wave ILP, was the build bottleneck).
// Payload stores go to the shard's private 300KB pairs region (block b -> XCD
// b%8 fixed by round-robin dispatch -> writes stay XCD-local). Final counters
// are flushed LDS->cfil once at block end, which also kills the memset.
// Convert blocks (proven round-2 4-wide form) trail behind and stream under
// the scatter blocks' latency.
__global__ __launch_bounds__(256) void build_kernel(
    const int* __restrict__ row, const int* __restrict__ col,
    int* __restrict__ cfil, int* __restrict__ pairs,
    const float* __restrict__ user, const float* __restrict__ item,
    _Float16* __restrict__ x16) {
    int b = blockIdx.x;
    if (b < NSH) {
        __shared__ int lcnt[NB];
        int t = threadIdx.x;
        for (int i = t; i < NB; i += 256) lcnt[i] = 0;
        __syncthreads();
        int base = b * PPS;
        int lim = min(NP - base, PPS);
        int* pb = pairs + (size_t)b * NB * CAP;
        for (int i = t; i < lim; i += 256) {
            int k = base + i;
            int u = row[k];          // user id (target of direction 2)
            int v = col[k];          // item id (target of direction 1)
            int c1 = v >> 6;
            int p1 = atomicAdd(&lcnt[c1], 1);
            if (p1 < CAP) pb[c1 * CAP + p1] = (u << 6) | (v & 63);
            int c2 = u >> 6;
            int p2 = atomicAdd(&lcnt[c2], 1);
            if (p2 < CAP) pb[c2 * CAP + p2] = (v << 6) | (u & 63);
        }
        __syncthreads();
        for (int i = t; i < NB; i += 256) cfil[b * NB + i] = lcnt[i];
    } else {
        size_t t = (size_t)(b - NSH) * 256 + threadIdx.x;   // group of 4 floats
        size_t e = t * 4;
        if (e < (size_t)NN * DIM) {
            const size_t NUsz = (size_t)NU * DIM;
            float4 v = (e < NUsz) ? *(const float4*)(user + e)
                                  : *(const float4*)(item + (e - NUsz));
            half4c h;
            h[0] = (_Float16)v.x; h[1] = (_Float16)v.y;
            h[2] = (_Float16)v.z; h[3] = (_Float16)v.w;
            *(half4c*)(x16 + e) = h;
        }
    }
}

// Per bucket: read its 128 cells, LDS-count per node, wave-scan -> ptr/deg/dinv,
// then compact into the bucket's static adj region [b*BCAP, ...).
__global__ __launch_bounds__(256) void place_kernel(
    const int* __restrict__ cfil, const int* __restrict__ pairs,
    int* __restrict__ adj, int* __restrict__ ptr, int* __restrict__ deg,
    float* __restrict__ dinv) {
    __shared__ int lcnt[64];
    __shared__ int lptr[64];
    __shared__ int lfill[64];
    __shared__ int llen[NSH];
    int b = blockIdx.x;
    int t = threadIdx.x;
    if (t < 64) {
        lcnt[t] = 0;
        lfill[t] = 0;
    }
    if (t < NSH) llen[t] = min(cfil[t * NB + b], CAP);
    __syncthreads();
    // count: 16 threads per cell, 16 cells per pass
    for (int s = t >> 4; s < NSH; s += 16) {
        const int* cp = pairs + (size_t)(s * NB + b) * CAP;
        int len = llen[s];
        for (int i = t & 15; i < len; i += 16)
            atomicAdd(&lcnt[cp[i] & 63], 1);
    }
    __syncthreads();
    if (t < 64) {   // threads 0..63 = lanes 0..63 of wave 0
        int v = lcnt[t];
        int incl = v;
        #pragma unroll
        for (int off = 1; off < 64; off <<= 1) {
            int u = __shfl_up(incl, off, 64);
            if (t >= off) incl += u;
        }
        lptr[t] = (b << 12) + incl - v;   // bucket's static adj base + prefix
        int c = (b << 6) + t;
        if (c < NN) {
            ptr[c] = lptr[t];
            deg[c] = v;
            dinv[c] = (v > 0) ? 1.0f / sqrtf((float)v) : 0.0f;
        }
    }
    __syncthreads();
    // place
    for (int s = t >> 4; s < NSH; s += 16) {
        const int* cp = pairs + (size_t)(s * NB + b) * CAP;
        int len = llen[s];
        for (int i = t & 15; i < len; i += 16) {
            int pk = cp[i];
            int lc = pk & 63;
            int slot = lptr[lc] + atomicAdd(&lfill[lc], 1);
            adj[slot] = pk >> 6;
        }
    }
}

// ---------------- propagation (wide-gather, unroll-2) ----------------
// One wave per target node. 16 lanes cover one 256B row (8 halves/lane);
// 4 quads x 2 unrolled slots = 8 edges / iteration, 16 lines in flight.
// fp32 accumulate; fabric-roofline-bound (~3.58 TB/s effective, FETCH ~= 287 MB
// ~= per-XCD compulsory line coverage with private L2s). Plain loads/stores
// only — nt hints measured net-negative here (round 4: 104 -> 116 us).
__global__ __launch_bounds__(256) void prop_kernel(
    const _Float16* __restrict__ xin,
    const float* __restrict__ dinv, const int* __restrict__ ptr,
    const int* __restrict__ deg, const int* __restrict__ adj,
    _Float16* __restrict__ xout, int finalize,
    const _Float16* __restrict__ x0, const _Float16* __restrict__ x1,
    const _Float16* __restrict__ x2, float* __restrict__ out)
{
    int wid = (blockIdx.x * blockDim.x + threadIdx.x) >> 6;
    if (wid >= NN) return;
    int lane = threadIdx.x & 63;
    int q = lane >> 4;     // edge sub-slot 0..3
    int m = lane & 15;     // halves [8m, 8m+8) of the row
    int beg = ptr[wid];
    int end = beg + deg[wid];

    float a0 = 0.f, a1 = 0.f, a2 = 0.f, a3 = 0.f;
    float a4 = 0.f, a5 = 0.f, a6 = 0.f, a7 = 0.f;
    int j = beg;
    for (; j + 8 <= end; j += 8) {
        int r0 = adj[j + q];
        int r1 = adj[j + 4 + q];
        float w0 = dinv[r0];
        float w1 = dinv[r1];
        half8 v0 = *(const half8*)(xin + (size_t)r0 * DIM + 8 * m);
        half8 v1 = *(const half8*)(xin + (size_t)r1 * DIM + 8 * m);
        a0 += w0 * (float)v0[0] + w1 * (float)v1[0];
        a1 += w0 * (float)v0[1] + w1 * (float)v1[1];
        a2 += w0 * (float)v0[2] + w1 * (float)v1[2];
        a3 += w0 * (float)v0[3] + w1 * (float)v1[3];
        a4 += w0 * (float)v0[4] + w1 * (float)v1[4];
        a5 += w0 * (float)v0[5] + w1 * (float)v1[5];
        a6 += w0 * (float)v0[6] + w1 * (float)v1[6];
        a7 += w0 * (float)v0[7] + w1 * (float)v1[7];
    }
    if (j < end) {
        int jj0 = j + q;
        int jj1 = j + 4 + q;
        int r0 = adj[min(jj0, end - 1)];
        int r1 = adj[min(jj1, end - 1)];
        float w0 = (jj0 < end) ? dinv[r0] : 0.f;
        float w1 = (jj1 < end) ? dinv[r1] : 0.f;
        half8 v0 = *(const half8*)(xin + (size_t)r0 * DIM + 8 * m);
        half8 v1 = *(const half8*)(xin + (size_t)r1 * DIM + 8 * m);
        a0 += w0 * (float)v0[0] + w1 * (float)v1[0];
        a1 += w0 * (float)v0[1] + w1 * (float)v1[1];
        a2 += w0 * (float)v0[2] + w1 * (float)v1[2];
        a3 += w0 * (float)v0[3] + w1 * (float)v1[3];
        a4 += w0 * (float)v0[4] + w1 * (float)v1[4];
        a5 += w0 * (float)v0[5] + w1 * (float)v1[5];
        a6 += w0 * (float)v0[6] + w1 * (float)v1[6];
        a7 += w0 * (float)v0[7] + w1 * (float)v1[7];
    }
    a0 += __shfl_xor(a0, 16, 64); a1 += __shfl_xor(a1, 16, 64);
    a2 += __shfl_xor(a2, 16, 64); a3 += __shfl_xor(a3, 16, 64);
    a4 += __shfl_xor(a4, 16, 64); a5 += __shfl_xor(a5, 16, 64);
    a6 += __shfl_xor(a6, 16, 64); a7 += __shfl_xor(a7, 16, 64);
    a0 += __shfl_xor(a0, 32, 64); a1 += __shfl_xor(a1, 32, 64);
    a2 += __shfl_xor(a2, 32, 64); a3 += __shfl_xor(a3, 32, 64);
    a4 += __shfl_xor(a4, 32, 64); a5 += __shfl_xor(a5, 32, 64);
    a6 += __shfl_xor(a6, 32, 64); a7 += __shfl_xor(a7, 32, 64);

    if (q != 0) return;
    float dc = dinv[wid];
    float n0 = dc * a0, n1 = dc * a1, n2 = dc * a2, n3 = dc * a3;
    float n4 = dc * a4, n5 = dc * a5, n6 = dc * a6, n7 = dc * a7;

    if (!finalize) {
        half8 h;
        h[0] = (_Float16)n0; h[1] = (_Float16)n1; h[2] = (_Float16)n2; h[3] = (_Float16)n3;
        h[4] = (_Float16)n4; h[5] = (_Float16)n5; h[6] = (_Float16)n6; h[7] = (_Float16)n7;
        *(half8*)(xout + (size_t)wid * DIM + 8 * m) = h;
    } else {
        size_t base = (size_t)wid * DIM + 8 * m;
        half8 f0 = *(const half8*)(x0 + base);
        half8 f1 = *(const half8*)(x1 + base);
        half8 f2 = *(const half8*)(x2 + base);
        float* po = out + base;
        float4 oa, ob;
        oa.x = ((float)f0[0] + (float)f1[0] + (float)f2[0] + n0) * 0.25f;
        oa.y = ((float)f0[1] + (float)f1[1] + (float)f2[1] + n1) * 0.25f;
        oa.z = ((float)f0[2] + (float)f1[2] + (float)f2[2] + n2) * 0.25f;
        oa.w = ((float)f0[3] + (float)f1[3] + (float)f2[3] + n3) * 0.25f;
        ob.x = ((float)f0[4] + (float)f1[4] + (float)f2[4] + n4) * 0.25f;
        ob.y = ((float)f0[5] + (float)f1[5] + (float)f2[5] + n5) * 0.25f;
        ob.z = ((float)f0[6] + (float)f1[6] + (float)f2[6] + n6) * 0.25f;
        ob.w = ((float)f0[7] + (float)f1[7] + (float)f2[7] + n7) * 0.25f;
        *(float4*)(po) = oa;
        *(float4*)(po + 4) = ob;
    }
}

// ---------------- launch ----------------

extern "C" void kernel_launch(void* const* d_in, const int* in_sizes, int n_in,
                              void* d_out, int out_size, void* d_ws, size_t ws_size,
                              hipStream_t stream) {
    const int* edge = (const int*)d_in[0];      // [2, NE] int32
    const int* row = edge;                      // sources (first NP entries = users)
    const int* col = edge + NE;                 // targets (first NP entries = items)
    const float* user = (const float*)d_in[1];  // [NU, DIM]
    const float* item = (const float*)d_in[2];  // [NI, DIM]
    float* out = (float*)d_out;                 // [NN, DIM]

    char* ws = (char*)d_ws;
    size_t off = 0;
    auto alloc = [&](size_t bytes) -> void* {
        void* p = ws + off;
        off = (off + bytes + 255) & ~(size_t)255;
        return p;
    };
    _Float16* x0 = (_Float16*)alloc(sizeof(_Float16) * (size_t)NN * DIM);  // 38.4 MB
    _Float16* x1 = (_Float16*)alloc(sizeof(_Float16) * (size_t)NN * DIM);
    _Float16* x2 = (_Float16*)alloc(sizeof(_Float16) * (size_t)NN * DIM);
    float* dinv = (float*)alloc(sizeof(float) * NN);
    int*   cfil = (int*)  alloc(sizeof(int) * NSH * NB);              // 1.2 MB (written by scatter)
    int*   ptr  = (int*)  alloc(sizeof(int) * NN);
    int*   deg  = (int*)  alloc(sizeof(int) * NN);
    int*   pairs= (int*)  alloc(sizeof(int) * (size_t)NSH * NB * CAP);// 38.4 MB
    int*   adj  = (int*)  alloc(sizeof(int) * (size_t)NB * BCAP);     // 38.4 MB

    build_kernel<<<NSH + CVB, 256, 0, stream>>>(row, col, cfil, pairs, user, item, x0);
    place_kernel<<<NB, 256, 0, stream>>>(cfil, pairs, adj, ptr, deg, dinv);

    int blocks = (NN + 3) / 4;  // 4 waves (nodes) per 256-thread block
    prop_kernel<<<blocks, 256, 0, stream>>>(x0, dinv, ptr, deg, adj, x1, 0,
                                            nullptr, nullptr, nullptr, nullptr);
    prop_kernel<<<blocks, 256, 0, stream>>>(x1, dinv, ptr, deg, adj, x2, 0,
                                            nullptr, nullptr, nullptr, nullptr);
    prop_kernel<<<blocks, 256, 0, stream>>>(x2, dinv, ptr, deg, adj, nullptr, 1,
                                            x0, x1, x2, out);
}

// Round 7
// 462.278 us; speedup vs baseline: 1.0802x; 1.0198x over previous
//
#include <hip/hip_runtime.h>

#define NU 100000      // users
#define NI 50000       // items
#define NN 150000      // total nodes
#define DIM 128        // embedding dim
#define NE 2000000     // directed edges (symmetrized)
#define NP 1000000     // undirected pairs (edge k and k+NP are the two directions)
#define NB ((NN + 63) / 64)   // 2344 64-node buckets
#define NSH 128               // scatter shards == scatter blocks (one block per shard)
#define CAP 32                // slots per (shard,bucket) cell = exactly one 128B line;
                              // Poisson(6.7) P(>32)*300K cells ~ 3e-8
#define BCAP 4096             // adj entries reserved per bucket (64 nodes x 64)

typedef _Float16 half8 __attribute__((ext_vector_type(8)));
typedef _Float16 half4c __attribute__((ext_vector_type(4)));

#define PPS ((NP + NSH - 1) / NSH)            // 7813 pairs per shard block
#define CVB ((NN * DIM / 4 + 255) / 256)      // 18750 convert blocks (exact)

// ---------------- scatter: LDS-counter sharded scatter ----------------
// One block per shard: the shard's 2344 cell counters live in LDS (zero global
// atomics — round-6 win). Payload stores go to the shard's private 300KB pairs
// region. Counter flush is TRANSPOSED (cfil[bucket][shard]) so place reads its
// 128 lengths as 4 coalesced lines instead of 128 scattered words.
__global__ __launch_bounds__(256) void scatter_kernel(
    const int* __restrict__ row, const int* __restrict__ col,
    int* __restrict__ cfil, int* __restrict__ pairs) {
    __shared__ int lcnt[NB];
    int b = blockIdx.x;
    int t = threadIdx.x;
    for (int i = t; i < NB; i += 256) lcnt[i] = 0;
    __syncthreads();
    int base = b * PPS;
    int lim = min(NP - base, PPS);
    int* pb = pairs + (size_t)b * NB * CAP;
    for (int i = t; i < lim; i += 256) {
        int k = base + i;
        int u = row[k];          // user id (target of direction 2)
        int v = col[k];          // item id (target of direction 1)
        int c1 = v >> 6;
        int p1 = atomicAdd(&lcnt[c1], 1);
        if (p1 < CAP) pb[c1 * CAP + p1] = (u << 6) | (v & 63);
        int c2 = u >> 6;
        int p2 = atomicAdd(&lcnt[c2], 1);
        if (p2 < CAP) pb[c2 * CAP + p2] = (v << 6) | (u & 63);
    }
    __syncthreads();
    for (int i = t; i < NB; i += 256) cfil[i * NSH + b] = min(lcnt[i], CAP);
}

// ---------------- place (+ fused fp16 convert) ----------------
// Place blocks (blk < NB): stage the bucket's 128 cells (128 x 128B = 16 KB)
// into LDS with fully dense line reads (each half-wave reads one whole line),
// then count/scan/place entirely from LDS — ONE sparse-free pass over pairs
// instead of round-6's two passes of 16-lane reads on 6.7-entry cells.
// Convert blocks (blk >= NB) are independent streaming work (proven round-2
// form) riding under the place blocks' staging latency.
__global__ __launch_bounds__(256) void place_kernel(
    const int* __restrict__ cfil, const int* __restrict__ pairs,
    int* __restrict__ adj, int* __restrict__ ptr, int* __restrict__ deg,
    float* __restrict__ dinv,
    const float* __restrict__ user, const float* __restrict__ item,
    _Float16* __restrict__ x16) {
    __shared__ int lp[NSH * CAP];   // 16 KB staged slots
    __shared__ int llen[NSH];
    __shared__ int lcnt[64];
    __shared__ int lptr[64];
    __shared__ int lfill[64];
    int blk = blockIdx.x;
    int t = threadIdx.x;
    if (blk < NB) {
        int b = blk;
        if (t < NSH) llen[t] = cfil[b * NSH + t];
        if (t < 64) { lcnt[t] = 0; lfill[t] = 0; }
        __syncthreads();
        // stage: slot = s*CAP + i  <-  pairs[(s*NB + b)*CAP + i]
        #pragma unroll
        for (int slot = t; slot < NSH * CAP; slot += 256) {
            int s = slot >> 5;          // CAP = 32
            int i = slot & 31;
            lp[slot] = pairs[((size_t)s * NB + b) * CAP + i];
        }
        __syncthreads();
        // count (from LDS)
        #pragma unroll
        for (int slot = t; slot < NSH * CAP; slot += 256) {
            if ((slot & 31) < llen[slot >> 5])
                atomicAdd(&lcnt[lp[slot] & 63], 1);
        }
        __syncthreads();
        if (t < 64) {   // threads 0..63 = lanes 0..63 of wave 0
            int v = lcnt[t];
            int incl = v;
            #pragma unroll
            for (int off = 1; off < 64; off <<= 1) {
                int u = __shfl_up(incl, off, 64);
                if (t >= off) incl += u;
            }
            lptr[t] = (b << 12) + incl - v;   // bucket's static adj base + prefix
            int c = (b << 6) + t;
            if (c < NN) {
                ptr[c] = lptr[t];
                deg[c] = v;
                dinv[c] = (v > 0) ? 1.0f / sqrtf((float)v) : 0.0f;
            }
        }
        __syncthreads();
        // place (from LDS)
        #pragma unroll
        for (int slot = t; slot < NSH * CAP; slot += 256) {
            if ((slot & 31) < llen[slot >> 5]) {
                int pk = lp[slot];
                int lc = pk & 63;
                int so = lptr[lc] + atomicAdd(&lfill[lc], 1);
                adj[so] = pk >> 6;
            }
        }
    } else {
        size_t tt = (size_t)(blk - NB) * 256 + t;   // group of 4 floats
        size_t e = tt * 4;
        if (e < (size_t)NN * DIM) {
            const size_t NUsz = (size_t)NU * DIM;
            float4 v = (e < NUsz) ? *(const float4*)(user + e)
                                  : *(const float4*)(item + (e - NUsz));
            half4c h;
            h[0] = (_Float16)v.x; h[1] = (_Float16)v.y;
            h[2] = (_Float16)v.z; h[3] = (_Float16)v.w;
            *(half4c*)(x16 + e) = h;
        }
    }
}

// ---------------- propagation (wide-gather, unroll-2) ----------------
// One wave per target node. 16 lanes cover one 256B row (8 halves/lane);
// 4 quads x 2 unrolled slots = 8 edges / iteration, 16 lines in flight.
// fp32 accumulate; fabric-roofline-bound (~3.58 TB/s effective, FETCH ~= 287 MB
// ~= per-XCD distinct-coverage floor with private L2s). Plain loads/stores
// only — nt hints measured net-negative here (round 4: 104 -> 116 us).
__global__ __launch_bounds__(256) void prop_kernel(
    const _Float16* __restrict__ xin,
    const float* __restrict__ dinv, const int* __restrict__ ptr,
    const int* __restrict__ deg, const int* __restrict__ adj,
    _Float16* __restrict__ xout, int finalize,
    const _Float16* __restrict__ x0, const _Float16* __restrict__ x1,
    const _Float16* __restrict__ x2, float* __restrict__ out)
{
    int wid = (blockIdx.x * blockDim.x + threadIdx.x) >> 6;
    if (wid >= NN) return;
    int lane = threadIdx.x & 63;
    int q = lane >> 4;     // edge sub-slot 0..3
    int m = lane & 15;     // halves [8m, 8m+8) of the row
    int beg = ptr[wid];
    int end = beg + deg[wid];

    float a0 = 0.f, a1 = 0.f, a2 = 0.f, a3 = 0.f;
    float a4 = 0.f, a5 = 0.f, a6 = 0.f, a7 = 0.f;
    int j = beg;
    for (; j + 8 <= end; j += 8) {
        int r0 = adj[j + q];
        int r1 = adj[j + 4 + q];
        float w0 = dinv[r0];
        float w1 = dinv[r1];
        half8 v0 = *(const half8*)(xin + (size_t)r0 * DIM + 8 * m);
        half8 v1 = *(const half8*)(xin + (size_t)r1 * DIM + 8 * m);
        a0 += w0 * (float)v0[0] + w1 * (float)v1[0];
        a1 += w0 * (float)v0[1] + w1 * (float)v1[1];
        a2 += w0 * (float)v0[2] + w1 * (float)v1[2];
        a3 += w0 * (float)v0[3] + w1 * (float)v1[3];
        a4 += w0 * (float)v0[4] + w1 * (float)v1[4];
        a5 += w0 * (float)v0[5] + w1 * (float)v1[5];
        a6 += w0 * (float)v0[6] + w1 * (float)v1[6];
        a7 += w0 * (float)v0[7] + w1 * (float)v1[7];
    }
    if (j < end) {
        int jj0 = j + q;
        int jj1 = j + 4 + q;
        int r0 = adj[min(jj0, end - 1)];
        int r1 = adj[min(jj1, end - 1)];
        float w0 = (jj0 < end) ? dinv[r0] : 0.f;
        float w1 = (jj1 < end) ? dinv[r1] : 0.f;
        half8 v0 = *(const half8*)(xin + (size_t)r0 * DIM + 8 * m);
        half8 v1 = *(const half8*)(xin + (size_t)r1 * DIM + 8 * m);
        a0 += w0 * (float)v0[0] + w1 * (float)v1[0];
        a1 += w0 * (float)v0[1] + w1 * (float)v1[1];
        a2 += w0 * (float)v0[2] + w1 * (float)v1[2];
        a3 += w0 * (float)v0[3] + w1 * (float)v1[3];
        a4 += w0 * (float)v0[4] + w1 * (float)v1[4];
        a5 += w0 * (float)v0[5] + w1 * (float)v1[5];
        a6 += w0 * (float)v0[6] + w1 * (float)v1[6];
        a7 += w0 * (float)v0[7] + w1 * (float)v1[7];
    }
    a0 += __shfl_xor(a0, 16, 64); a1 += __shfl_xor(a1, 16, 64);
    a2 += __shfl_xor(a2, 16, 64); a3 += __shfl_xor(a3, 16, 64);
    a4 += __shfl_xor(a4, 16, 64); a5 += __shfl_xor(a5, 16, 64);
    a6 += __shfl_xor(a6, 16, 64); a7 += __shfl_xor(a7, 16, 64);
    a0 += __shfl_xor(a0, 32, 64); a1 += __shfl_xor(a1, 32, 64);
    a2 += __shfl_xor(a2, 32, 64); a3 += __shfl_xor(a3, 32, 64);
    a4 += __shfl_xor(a4, 32, 64); a5 += __shfl_xor(a5, 32, 64);
    a6 += __shfl_xor(a6, 32, 64); a7 += __shfl_xor(a7, 32, 64);

    if (q != 0) return;
    float dc = dinv[wid];
    float n0 = dc * a0, n1 = dc * a1, n2 = dc * a2, n3 = dc * a3;
    float n4 = dc * a4, n5 = dc * a5, n6 = dc * a6, n7 = dc * a7;

    if (!finalize) {
        half8 h;
        h[0] = (_Float16)n0; h[1] = (_Float16)n1; h[2] = (_Float16)n2; h[3] = (_Float16)n3;
        h[4] = (_Float16)n4; h[5] = (_Float16)n5; h[6] = (_Float16)n6; h[7] = (_Float16)n7;
        *(half8*)(xout + (size_t)wid * DIM + 8 * m) = h;
    } else {
        size_t base = (size_t)wid * DIM + 8 * m;
        half8 f0 = *(const half8*)(x0 + base);
        half8 f1 = *(const half8*)(x1 + base);
        half8 f2 = *(const half8*)(x2 + base);
        float* po = out + base;
        float4 oa, ob;
        oa.x = ((float)f0[0] + (float)f1[0] + (float)f2[0] + n0) * 0.25f;
        oa.y = ((float)f0[1] + (float)f1[1] + (float)f2[1] + n1) * 0.25f;
        oa.z = ((float)f0[2] + (float)f1[2] + (float)f2[2] + n2) * 0.25f;
        oa.w = ((float)f0[3] + (float)f1[3] + (float)f2[3] + n3) * 0.25f;
        ob.x = ((float)f0[4] + (float)f1[4] + (float)f2[4] + n4) * 0.25f;
        ob.y = ((float)f0[5] + (float)f1[5] + (float)f2[5] + n5) * 0.25f;
        ob.z = ((float)f0[6] + (float)f1[6] + (float)f2[6] + n6) * 0.25f;
        ob.w = ((float)f0[7] + (float)f1[7] + (float)f2[7] + n7) * 0.25f;
        *(float4*)(po) = oa;
        *(float4*)(po + 4) = ob;
    }
}

// ---------------- launch ----------------

extern "C" void kernel_launch(void* const* d_in, const int* in_sizes, int n_in,
                              void* d_out, int out_size, void* d_ws, size_t ws_size,
                              hipStream_t stream) {
    const int* edge = (const int*)d_in[0];      // [2, NE] int32
    const int* row = edge;                      // sources (first NP entries = users)
    const int* col = edge + NE;                 // targets (first NP entries = items)
    const float* user = (const float*)d_in[1];  // [NU, DIM]
    const float* item = (const float*)d_in[2];  // [NI, DIM]
    float* out = (float*)d_out;                 // [NN, DIM]

    char* ws = (char*)d_ws;
    size_t off = 0;
    auto alloc = [&](size_t bytes) -> void* {
        void* p = ws + off;
        off = (off + bytes + 255) & ~(size_t)255;
        return p;
    };
    _Float16* x0 = (_Float16*)alloc(sizeof(_Float16) * (size_t)NN * DIM);  // 38.4 MB
    _Float16* x1 = (_Float16*)alloc(sizeof(_Float16) * (size_t)NN * DIM);
    _Float16* x2 = (_Float16*)alloc(sizeof(_Float16) * (size_t)NN * DIM);
    float* dinv = (float*)alloc(sizeof(float) * NN);
    int*   cfil = (int*)  alloc(sizeof(int) * NSH * NB);              // 1.2 MB (written by scatter)
    int*   ptr  = (int*)  alloc(sizeof(int) * NN);
    int*   deg  = (int*)  alloc(sizeof(int) * NN);
    int*   pairs= (int*)  alloc(sizeof(int) * (size_t)NSH * NB * CAP);// 38.4 MB
    int*   adj  = (int*)  alloc(sizeof(int) * (size_t)NB * BCAP);     // 38.4 MB

    scatter_kernel<<<NSH, 256, 0, stream>>>(row, col, cfil, pairs);
    place_kernel<<<NB + CVB, 256, 0, stream>>>(cfil, pairs, adj, ptr, deg, dinv,
                                               user, item, x0);

    int blocks = (NN + 3) / 4;  // 4 waves (nodes) per 256-thread block
    prop_kernel<<<blocks, 256, 0, stream>>>(x0, dinv, ptr, deg, adj, x1, 0,
                                            nullptr, nullptr, nullptr, nullptr);
    prop_kernel<<<blocks, 256, 0, stream>>>(x1, dinv, ptr, deg, adj, x2, 0,
                                            nullptr, nullptr, nullptr, nullptr);
    prop_kernel<<<blocks, 256, 0, stream>>>(x2, dinv, ptr, deg, adj, nullptr, 1,
                                            x0, x1, x2, out);
}

// Round 9
// 454.138 us; speedup vs baseline: 1.0995x; 1.0179x over previous
//
#include <hip/hip_runtime.h>

#define NU 100000      // users
#define NI 50000       // items
#define NN 150000      // total nodes
#define DIM 128        // embedding dim
#define NE 2000000     // directed edges (symmetrized)
#define NP 1000000     // undirected pairs (edge k and k+NP are the two directions)
#define NB ((NN + 63) / 64)   // 2344 64-node buckets
#define NSH 128               // scatter shards
#define QSPLIT 4              // sub-blocks per shard (bucket mod-4 interleave)
#define QB ((NB + QSPLIT - 1) / QSPLIT)   // 586 LDS counters per sub-block
#define CAP 32                // slots per (shard,bucket) cell = one 128B line;
                              // Poisson(6.7) P(>32)*300K cells ~ 3e-8
#define BCAP 4096             // adj entries reserved per bucket (64 nodes x 64)

typedef _Float16 half8 __attribute__((ext_vector_type(8)));
typedef _Float16 half4c __attribute__((ext_vector_type(4)));

#define PPS ((NP + NSH - 1) / NSH)            // 7813 pairs per shard
#define CVB ((NN * DIM / 4 + 255) / 256)      // 18750 convert blocks (exact)

// ---------------- scatter: LDS-counter sharded scatter, 4-way split ----------------
// 512 blocks = 128 shards x 4 sub-blocks. Sub-block (s,q) scans shard s's full
// pair range but handles only directions whose target bucket ≡ q (mod 4); its
// 586 cell counters live in LDS (zero global atomics). s = blockIdx&127,
// q = blockIdx>>7 puts all 4 sub-blocks of a shard on ONE XCD (128%8==0 under
// round-robin dispatch): edge re-reads are L2-hits and the shard's pairs
// region stays XCD-local. 4x the latency-hiding of round-7's 128-block form.
// Counter flush is transposed (cfil[bucket][shard]) for place's coalesced read.
__global__ __launch_bounds__(256) void scatter_kernel(
    const int* __restrict__ row, const int* __restrict__ col,
    int* __restrict__ cfil, int* __restrict__ pairs) {
    __shared__ int lcnt[QB];
    int s = blockIdx.x & (NSH - 1);
    int q = blockIdx.x >> 7;
    int t = threadIdx.x;
    for (int i = t; i < QB; i += 256) lcnt[i] = 0;
    __syncthreads();
    int base = s * PPS;
    int lim = min(NP - base, PPS);
    int* pb = pairs + (size_t)s * NB * CAP;
    for (int i = t; i < lim; i += 256) {
        int k = base + i;
        int u = row[k];          // user id (target of direction 2)
        int v = col[k];          // item id (target of direction 1)
        int c1 = v >> 6;
        if ((c1 & 3) == q) {
            int p1 = atomicAdd(&lcnt[c1 >> 2], 1);
            if (p1 < CAP) pb[c1 * CAP + p1] = (u << 6) | (v & 63);
        }
        int c2 = u >> 6;
        if ((c2 & 3) == q) {
            int p2 = atomicAdd(&lcnt[c2 >> 2], 1);
            if (p2 < CAP) pb[c2 * CAP + p2] = (v << 6) | (u & 63);
        }
    }
    __syncthreads();
    for (int i = t; i < QB; i += 256) {
        int b = (i << 2) | q;
        if (b < NB) cfil[b * NSH + s] = min(lcnt[i], CAP);
    }
}

// ---------------- place (+ fused fp16 convert) ----------------
// Place blocks (blk < NB): stage the bucket's 128 cells (128 x 128B = 16 KB)
// into LDS with fully dense line reads, then count/scan/place entirely from
// LDS — one sparse-free pass over pairs. Convert blocks (blk >= NB) are
// independent streaming work riding under the place blocks' staging latency.
__global__ __launch_bounds__(256) void place_kernel(
    const int* __restrict__ cfil, const int* __restrict__ pairs,
    int* __restrict__ adj, int* __restrict__ ptr, int* __restrict__ deg,
    float* __restrict__ dinv,
    const float* __restrict__ user, const float* __restrict__ item,
    _Float16* __restrict__ x16) {
    __shared__ int lp[NSH * CAP];   // 16 KB staged slots
    __shared__ int llen[NSH];
    __shared__ int lcnt[64];
    __shared__ int lptr[64];
    __shared__ int lfill[64];
    int blk = blockIdx.x;
    int t = threadIdx.x;
    if (blk < NB) {
        int b = blk;
        if (t < NSH) llen[t] = cfil[b * NSH + t];
        if (t < 64) { lcnt[t] = 0; lfill[t] = 0; }
        __syncthreads();
        // stage: slot = s*CAP + i  <-  pairs[(s*NB + b)*CAP + i]
        #pragma unroll
        for (int slot = t; slot < NSH * CAP; slot += 256) {
            int s = slot >> 5;          // CAP = 32
            int i = slot & 31;
            lp[slot] = pairs[((size_t)s * NB + b) * CAP + i];
        }
        __syncthreads();
        // count (from LDS)
        #pragma unroll
        for (int slot = t; slot < NSH * CAP; slot += 256) {
            if ((slot & 31) < llen[slot >> 5])
                atomicAdd(&lcnt[lp[slot] & 63], 1);
        }
        __syncthreads();
        if (t < 64) {   // threads 0..63 = lanes 0..63 of wave 0
            int v = lcnt[t];
            int incl = v;
            #pragma unroll
            for (int off = 1; off < 64; off <<= 1) {
                int u = __shfl_up(incl, off, 64);
                if (t >= off) incl += u;
            }
            lptr[t] = (b << 12) + incl - v;   // bucket's static adj base + prefix
            int c = (b << 6) + t;
            if (c < NN) {
                ptr[c] = lptr[t];
                deg[c] = v;
                dinv[c] = (v > 0) ? 1.0f / sqrtf((float)v) : 0.0f;
            }
        }
        __syncthreads();
        // place (from LDS)
        #pragma unroll
        for (int slot = t; slot < NSH * CAP; slot += 256) {
            if ((slot & 31) < llen[slot >> 5]) {
                int pk = lp[slot];
                int lc = pk & 63;
                int so = lptr[lc] + atomicAdd(&lfill[lc], 1);
                adj[so] = pk >> 6;
            }
        }
    } else {
        size_t tt = (size_t)(blk - NB) * 256 + t;   // group of 4 floats
        size_t e = tt * 4;
        if (e < (size_t)NN * DIM) {
            const size_t NUsz = (size_t)NU * DIM;
            float4 v = (e < NUsz) ? *(const float4*)(user + e)
                                  : *(const float4*)(item + (e - NUsz));
            half4c h;
            h[0] = (_Float16)v.x; h[1] = (_Float16)v.y;
            h[2] = (_Float16)v.z; h[3] = (_Float16)v.w;
            *(half4c*)(x16 + e) = h;
        }
    }
}

// ---------------- propagation (wide-gather, unroll-2) ----------------
// One wave per target node. 16 lanes cover one 256B row (8 halves/lane);
// 4 quads x 2 unrolled slots = 8 edges / iteration, 16 lines in flight.
// fp32 accumulate; fabric-roofline-bound (~3.58 TB/s effective, FETCH ~= 287 MB
// ~= per-XCD distinct-coverage floor with private L2s). Plain loads/stores
// only — nt hints measured net-negative here (round 4: 104 -> 116 us).
__global__ __launch_bounds__(256) void prop_kernel(
    const _Float16* __restrict__ xin,
    const float* __restrict__ dinv, const int* __restrict__ ptr,
    const int* __restrict__ deg, const int* __restrict__ adj,
    _Float16* __restrict__ xout, int finalize,
    const _Float16* __restrict__ x0, const _Float16* __restrict__ x1,
    const _Float16* __restrict__ x2, float* __restrict__ out)
{
    int wid = (blockIdx.x * blockDim.x + threadIdx.x) >> 6;
    if (wid >= NN) return;
    int lane = threadIdx.x & 63;
    int q = lane >> 4;     // edge sub-slot 0..3
    int m = lane & 15;     // halves [8m, 8m+8) of the row
    int beg = ptr[wid];
    int end = beg + deg[wid];

    float a0 = 0.f, a1 = 0.f, a2 = 0.f, a3 = 0.f;
    float a4 = 0.f, a5 = 0.f, a6 = 0.f, a7 = 0.f;
    int j = beg;
    for (; j + 8 <= end; j += 8) {
        int r0 = adj[j + q];
        int r1 = adj[j + 4 + q];
        float w0 = dinv[r0];
        float w1 = dinv[r1];
        half8 v0 = *(const half8*)(xin + (size_t)r0 * DIM + 8 * m);
        half8 v1 = *(const half8*)(xin + (size_t)r1 * DIM + 8 * m);
        a0 += w0 * (float)v0[0] + w1 * (float)v1[0];
        a1 += w0 * (float)v0[1] + w1 * (float)v1[1];
        a2 += w0 * (float)v0[2] + w1 * (float)v1[2];
        a3 += w0 * (float)v0[3] + w1 * (float)v1[3];
        a4 += w0 * (float)v0[4] + w1 * (float)v1[4];
        a5 += w0 * (float)v0[5] + w1 * (float)v1[5];
        a6 += w0 * (float)v0[6] + w1 * (float)v1[6];
        a7 += w0 * (float)v0[7] + w1 * (float)v1[7];
    }
    if (j < end) {
        int jj0 = j + q;
        int jj1 = j + 4 + q;
        int r0 = adj[min(jj0, end - 1)];
        int r1 = adj[min(jj1, end - 1)];
        float w0 = (jj0 < end) ? dinv[r0] : 0.f;
        float w1 = (jj1 < end) ? dinv[r1] : 0.f;
        half8 v0 = *(const half8*)(xin + (size_t)r0 * DIM + 8 * m);
        half8 v1 = *(const half8*)(xin + (size_t)r1 * DIM + 8 * m);
        a0 += w0 * (float)v0[0] + w1 * (float)v1[0];
        a1 += w0 * (float)v0[1] + w1 * (float)v1[1];
        a2 += w0 * (float)v0[2] + w1 * (float)v1[2];
        a3 += w0 * (float)v0[3] + w1 * (float)v1[3];
        a4 += w0 * (float)v0[4] + w1 * (float)v1[4];
        a5 += w0 * (float)v0[5] + w1 * (float)v1[5];
        a6 += w0 * (float)v0[6] + w1 * (float)v1[6];
        a7 += w0 * (float)v0[7] + w1 * (float)v1[7];
    }
    a0 += __shfl_xor(a0, 16, 64); a1 += __shfl_xor(a1, 16, 64);
    a2 += __shfl_xor(a2, 16, 64); a3 += __shfl_xor(a3, 16, 64);
    a4 += __shfl_xor(a4, 16, 64); a5 += __shfl_xor(a5, 16, 64);
    a6 += __shfl_xor(a6, 16, 64); a7 += __shfl_xor(a7, 16, 64);
    a0 += __shfl_xor(a0, 32, 64); a1 += __shfl_xor(a1, 32, 64);
    a2 += __shfl_xor(a2, 32, 64); a3 += __shfl_xor(a3, 32, 64);
    a4 += __shfl_xor(a4, 32, 64); a5 += __shfl_xor(a5, 32, 64);
    a6 += __shfl_xor(a6, 32, 64); a7 += __shfl_xor(a7, 32, 64);

    if (q != 0) return;
    float dc = dinv[wid];
    float n0 = dc * a0, n1 = dc * a1, n2 = dc * a2, n3 = dc * a3;
    float n4 = dc * a4, n5 = dc * a5, n6 = dc * a6, n7 = dc * a7;

    if (!finalize) {
        half8 h;
        h[0] = (_Float16)n0; h[1] = (_Float16)n1; h[2] = (_Float16)n2; h[3] = (_Float16)n3;
        h[4] = (_Float16)n4; h[5] = (_Float16)n5; h[6] = (_Float16)n6; h[7] = (_Float16)n7;
        *(half8*)(xout + (size_t)wid * DIM + 8 * m) = h;
    } else {
        size_t base = (size_t)wid * DIM + 8 * m;
        half8 f0 = *(const half8*)(x0 + base);
        half8 f1 = *(const half8*)(x1 + base);
        half8 f2 = *(const half8*)(x2 + base);
        float* po = out + base;
        float4 oa, ob;
        oa.x = ((float)f0[0] + (float)f1[0] + (float)f2[0] + n0) * 0.25f;
        oa.y = ((float)f0[1] + (float)f1[1] + (float)f2[1] + n1) * 0.25f;
        oa.z = ((float)f0[2] + (float)f1[2] + (float)f2[2] + n2) * 0.25f;
        oa.w = ((float)f0[3] + (float)f1[3] + (float)f2[3] + n3) * 0.25f;
        ob.x = ((float)f0[4] + (float)f1[4] + (float)f2[4] + n4) * 0.25f;
        ob.y = ((float)f0[5] + (float)f1[5] + (float)f2[5] + n5) * 0.25f;
        ob.z = ((float)f0[6] + (float)f1[6] + (float)f2[6] + n6) * 0.25f;
        ob.w = ((float)f0[7] + (float)f1[7] + (float)f2[7] + n7) * 0.25f;
        *(float4*)(po) = oa;
        *(float4*)(po + 4) = ob;
    }
}

// ---------------- launch ----------------

extern "C" void kernel_launch(void* const* d_in, const int* in_sizes, int n_in,
                              void* d_out, int out_size, void* d_ws, size_t ws_size,
                              hipStream_t stream) {
    const int* edge = (const int*)d_in[0];      // [2, NE] int32
    const int* row = edge;                      // sources (first NP entries = users)
    const int* col = edge + NE;                 // targets (first NP entries = items)
    const float* user = (const float*)d_in[1];  // [NU, DIM]
    const float* item = (const float*)d_in[2];  // [NI, DIM]
    float* out = (float*)d_out;                 // [NN, DIM]

    char* ws = (char*)d_ws;
    size_t off = 0;
    auto alloc = [&](size_t bytes) -> void* {
        void* p = ws + off;
        off = (off + bytes + 255) & ~(size_t)255;
        return p;
    };
    _Float16* x0 = (_Float16*)alloc(sizeof(_Float16) * (size_t)NN * DIM);  // 38.4 MB
    _Float16* x1 = (_Float16*)alloc(sizeof(_Float16) * (size_t)NN * DIM);
    _Float16* x2 = (_Float16*)alloc(sizeof(_Float16) * (size_t)NN * DIM);
    float* dinv = (float*)alloc(sizeof(float) * NN);
    int*   cfil = (int*)  alloc(sizeof(int) * NSH * NB);              // 1.2 MB (written by scatter)
    int*   ptr  = (int*)  alloc(sizeof(int) * NN);
    int*   deg  = (int*)  alloc(sizeof(int) * NN);
    int*   pairs= (int*)  alloc(sizeof(int) * (size_t)NSH * NB * CAP);// 38.4 MB
    int*   adj  = (int*)  alloc(sizeof(int) * (size_t)NB * BCAP);     // 38.4 MB

    scatter_kernel<<<NSH * QSPLIT, 256, 0, stream>>>(row, col, cfil, pairs);
    place_kernel<<<NB + CVB, 256, 0, stream>>>(cfil, pairs, adj, ptr, deg, dinv,
                                               user, item, x0);

    int blocks = (NN + 3) / 4;  // 4 waves (nodes) per 256-thread block
    prop_kernel<<<blocks, 256, 0, stream>>>(x0, dinv, ptr, deg, adj, x1, 0,
                                            nullptr, nullptr, nullptr, nullptr);
    prop_kernel<<<blocks, 256, 0, stream>>>(x1, dinv, ptr, deg, adj, x2, 0,
                                            nullptr, nullptr, nullptr, nullptr);
    prop_kernel<<<blocks, 256, 0, stream>>>(x2, dinv, ptr, deg, adj, nullptr, 1,
                                            x0, x1, x2, out);
}